// Round 1
// baseline (331.883 us; speedup 1.0000x reference)
//
#include <hip/hip_runtime.h>
#include <math.h>

#define N_ANT 64
#define BATCH 131072
#define NSTEPS 63   // 31 internal softmax units + 32 leaf groups, DFS preorder

typedef float v2f __attribute__((ext_vector_type(2)));

static __device__ __forceinline__ v2f vfma(v2f a, v2f b, v2f c) {
#if __has_builtin(__builtin_elementwise_fma)
    return __builtin_elementwise_fma(a, b, c);
#else
    v2f r; r.x = fmaf(a.x, b.x, c.x); r.y = fmaf(a.y, b.y, c.y); return r;
#endif
}

// Advance DFS-preorder state over the complete binary tree.
// Internal units: l=0..4 (node n at layer l). Leaf groups: l==5 (group n).
static __device__ __forceinline__ void dfs_next(int& l, int& n) {
    if (l < 5) { l = l + 1; n = 2 * n; }
    else {
        while (n & 1) { n >>= 1; l--; }
        n += 1;
    }
}

// Build combined real weight buffer in DFS-step order.
// Unit s occupies W[s*256 .. s*256+255]:
//   [  0.. 63] col0 w_re[a]   [ 64..127] col0 w_im[a]
//   [128..191] col1 w_re[a]   [192..255] col1 w_im[a]
__global__ void fill_weights(const float* __restrict__ t0, const float* __restrict__ t1,
                             const float* __restrict__ t2, const float* __restrict__ t3,
                             const float* __restrict__ t4, float* __restrict__ W) {
    const int s = blockIdx.x;
    const int a = threadIdx.x;  // antenna index 0..63
    int l = 0, n = 0;
    for (int i = 0; i < s; ++i) dfs_next(l, n);
    float* w = W + s * 256;
    const float inv = 0.125f;  // 1/sqrt(64)
    if (l < 5) {
        const float* th = (l == 0) ? t0 : (l == 1) ? t1 : (l == 2) ? t2 : (l == 3) ? t3 : t4;
        float th0 = th[(n * N_ANT + a) * 2 + 0];
        float th1 = th[(n * N_ANT + a) * 2 + 1];
        float s0, c0, s1, c1;
        sincosf(th0, &s0, &c0);
        sincosf(th1, &s1, &c1);
        w[0   + a] = c0 * inv;  w[64  + a] = s0 * inv;
        w[128 + a] = c1 * inv;  w[192 + a] = s1 * inv;
    } else {
        // Leaf DFT codebook columns 2n, 2n+1 (numpy computes in float64 then casts).
        const double step = (cos(M_PI - 1e-6) - 1.0) / 63.0;
        for (int k = 0; k < 2; ++k) {
            int c = 2 * n + k;
            double cosaz = 1.0 + (double)c * step;
            double ph = M_PI * (double)a * cosaz;
            w[128 * k + 0  + a] = (float)(cos(ph) * 0.125);
            w[128 * k + 64 + a] = (float)(sin(ph) * 0.125);
        }
    }
}

__global__ __launch_bounds__(256) void beam_tree(const float* __restrict__ x,
                                                 const float* __restrict__ W,
                                                 float* __restrict__ out) {
    // Per-thread 6-deep DFS probability stack in LDS; stride 13 words -> banks
    // (tid*13+k)%32 cover all 32 banks, 2 lanes/bank (free).
    __shared__ float stk[256 * 13];
    const int tid = threadIdx.x;
    const int e = blockIdx.x * 256 + tid;

    // Load x row: [re(0..63) | im(0..63)], keep fully in VGPRs as antenna pairs.
    const float4* px = (const float4*)(x + (size_t)e * 128);
    v2f xr[32], xi[32];
#pragma unroll
    for (int j = 0; j < 16; ++j) {
        float4 v = px[j];
        xr[2 * j]     = (v2f){v.x, v.y};
        xr[2 * j + 1] = (v2f){v.z, v.w};
    }
#pragma unroll
    for (int j = 0; j < 16; ++j) {
        float4 v = px[16 + j];
        xi[2 * j]     = (v2f){v.x, v.y};
        xi[2 * j + 1] = (v2f){v.z, v.w};
    }

    float* st = stk + tid * 13;
    float* o  = out + (size_t)e * 64;

    int l = 0, n = 0, g = 0;
    for (int s = 0; s < NSTEPS; ++s) {
        const float* wu = W + s * 256;  // uniform address -> SMEM (s_load) expected
        v2f arr = {0.f, 0.f}, ari = {0.f, 0.f}, air = {0.f, 0.f}, aii = {0.f, 0.f};
        v2f brr = {0.f, 0.f}, bri = {0.f, 0.f}, bir = {0.f, 0.f}, bii = {0.f, 0.f};
#pragma unroll
        for (int t = 0; t < 32; ++t) {
            v2f w0re = *(const v2f*)(wu + 2 * t);
            v2f w0im = *(const v2f*)(wu + 64 + 2 * t);
            v2f w1re = *(const v2f*)(wu + 128 + 2 * t);
            v2f w1im = *(const v2f*)(wu + 192 + 2 * t);
            arr = vfma(xr[t], w0re, arr);
            ari = vfma(xr[t], w0im, ari);
            air = vfma(xi[t], w0re, air);
            aii = vfma(xi[t], w0im, aii);
            brr = vfma(xr[t], w1re, brr);
            bri = vfma(xr[t], w1im, bri);
            bir = vfma(xi[t], w1re, bir);
            bii = vfma(xi[t], w1im, bii);
        }
        // y = sum_a h_a * w_a ; complex: re = xr*wre - xi*wim, im = xr*wim + xi*wre
        float y0r = (arr.x + arr.y) - (aii.x + aii.y);
        float y0i = (ari.x + ari.y) + (air.x + air.y);
        float y1r = (brr.x + brr.y) - (bii.x + bii.y);
        float y1i = (bri.x + bri.y) + (bir.x + bir.y);
        float g0 = fmaf(y0r, y0r, y0i * y0i);
        float g1 = fmaf(y1r, y1r, y1i * y1i);
        // 2-way softmax (max-subtracted, matches jax.nn.softmax)
        float m  = fmaxf(g0, g1);
        float e0 = __expf(g0 - m);
        float e1 = __expf(g1 - m);
        float inv = 1.0f / (e0 + e1);
        float p0 = e0 * inv, p1 = e1 * inv;

        float pme = (l == 0) ? 1.0f : st[(l - 1) * 2 + (n & 1)];
        if (l < 5) {
            st[l * 2 + 0] = pme * p0;
            st[l * 2 + 1] = pme * p1;
        } else {
            *(v2f*)(o + 2 * g) = (v2f){pme * p0, pme * p1};
            g++;
        }
        dfs_next(l, n);
    }
}

extern "C" void kernel_launch(void* const* d_in, const int* in_sizes, int n_in,
                              void* d_out, int out_size, void* d_ws, size_t ws_size,
                              hipStream_t stream) {
    const float* x  = (const float*)d_in[0];
    const float* t0 = (const float*)d_in[1];
    const float* t1 = (const float*)d_in[2];
    const float* t2 = (const float*)d_in[3];
    const float* t3 = (const float*)d_in[4];
    const float* t4 = (const float*)d_in[5];
    float* W = (float*)d_ws;  // 63*256*4 = 64.5 KB, rebuilt every call (ws re-poisoned)

    fill_weights<<<dim3(NSTEPS), dim3(N_ANT), 0, stream>>>(t0, t1, t2, t3, t4, W);
    beam_tree<<<dim3(BATCH / 256), dim3(256), 0, stream>>>(x, W, (float*)d_out);
}